// Round 4
// baseline (48.777 us; speedup 1.0000x reference)
//
#include <hip/hip_runtime.h>

typedef __bf16 bf16x8 __attribute__((ext_vector_type(8)));
typedef float f32x4 __attribute__((ext_vector_type(4)));

__device__ __forceinline__ unsigned short f2bf(float f) {
  __bf16 h = (__bf16)f;
  return __builtin_bit_cast(unsigned short, h);
}

// d_ws layout: [0, 24576) bytes: wsB bf16 fragment-ordered (12288 shorts)
//              [24576, 24832): bias (64 floats)
// wsB flat idx = (((di*4 + jblk)*2 + kstep)*64 + lane)*8 + i
//   c   = kstep*32 + 4*(lane>>4) + (i&3) + 16*(i>>2)
//   fch = jblk*16 + (lane&15)
// A uses the same (lane,i)->k bijection, so any consistent bijection is correct.
__global__ __launch_bounds__(256) void prep_kernel(
    const float* __restrict__ conv_w, const float* __restrict__ gamma,
    const float* __restrict__ beta, const float* __restrict__ mean,
    const float* __restrict__ var, unsigned short* __restrict__ wsB,
    float* __restrict__ bias) {
  int idx = blockIdx.x * 256 + threadIdx.x;
  if (idx >= 12288) return;
  int di    = idx >> 12;
  int r     = idx & 4095;
  int jblk  = r >> 10;
  int r2    = r & 1023;
  int kstep = r2 >> 9;
  int r3    = r2 & 511;
  int lane  = r3 >> 3;
  int i     = r3 & 7;
  int c   = kstep * 32 + 4 * (lane >> 4) + (i & 3) + 16 * (i >> 2);
  int fch = jblk * 16 + (lane & 15);
  float s = gamma[fch] * rsqrtf(var[fch] + 1e-3f);
  float v = conv_w[((di * 3 + 0) * 64 + c) * 64 + fch]
          + conv_w[((di * 3 + 1) * 64 + c) * 64 + fch]
          + conv_w[((di * 3 + 2) * 64 + c) * 64 + fch];
  wsB[idx] = f2bf(v * s);
  if (idx < 64) bias[idx] = beta[idx] - mean[idx] * (gamma[idx] * rsqrtf(var[idx] + 1e-3f));
}

__global__ __launch_bounds__(256, 4) void main_kernel(
    const float* __restrict__ fmap, const float* __restrict__ y2,
    const uint4* __restrict__ wsBq, const float* __restrict__ biasg,
    float* __restrict__ out) {
  __shared__ int   s_idx[4][384];
  __shared__ float s_wt[4][384];

  const int t    = threadIdx.x;
  const int lane = t & 63;
  const int wave = t >> 6;
  // XCD swizzle: pin one batch (4.2MB fmap ~ one XCD L2) per XCD
  const int b  = blockIdx.x & 7;
  const int oi = blockIdx.x >> 3;
  const float* fmapb = fmap + (size_t)b * (128 * 128 * 64);

  // ---- Phase 0: per-sample coords/weights (u = di*128 + up; j = u/3, a = u%3) ----
  for (int u = t; u < 384; u += 256) {
    int j = u / 3;
    int a = u - j * 3;
    const float4* yp = reinterpret_cast<const float4*>(
        y2 + ((size_t)(b * 128 + oi) * 128 + j) * 8);
    float4 xv = yp[0];
    float4 yv = yp[1];

    float hi01 = fmaxf(xv.x, xv.y), lo01 = fminf(xv.x, xv.y);
    float hi23 = fmaxf(xv.z, xv.w), lo23 = fminf(xv.z, xv.w);
    float top1 = fmaxf(hi01, hi23);
    float top2 = fmaxf(fminf(hi01, hi23), (hi01 >= hi23) ? lo01 : lo23);
    float w = fminf(fmaxf(top1, 1.f), 127.f) + fminf(fmaxf(top2, 1.f), 127.f);

    hi01 = fmaxf(yv.x, yv.y); lo01 = fminf(yv.x, yv.y);
    hi23 = fmaxf(yv.z, yv.w); lo23 = fminf(yv.z, yv.w);
    top1 = fmaxf(hi01, hi23);
    top2 = fmaxf(fminf(hi01, hi23), (hi01 >= hi23) ? lo01 : lo23);
    float h = fminf(fmaxf(top1, 1.f), 127.f) + fminf(fmaxf(top2, 1.f), 127.f);

    float x, yy;
    if (a == 0)      { x = ((float)j - 1.0f) - w / 3.0f;  yy = ((float)oi - 1.0f) - h / 3.0f; }
    else if (a == 1) { x = (float)j + w * 1e-10f;         yy = (float)oi + h * 1e-10f; }
    else             { x = ((float)j + 1.0f) + w / 3.0f;  yy = ((float)oi + 1.0f) + h / 3.0f; }

    float xl = fminf(fmaxf(floorf(x), 0.f), 127.f);
    float xr = fminf(fmaxf(ceilf(x),  0.f), 127.f);
    float yt = fminf(fmaxf(floorf(yy), 0.f), 127.f);
    float yb = fminf(fmaxf(ceilf(yy),  0.f), 127.f);
    int ixl = (int)xl, ixr = (int)xr, iyt = (int)yt, iyb = (int)yb;
    s_idx[0][u] = (iyt * 128 + ixl) * 64;  // lt
    s_idx[1][u] = (iyt * 128 + ixr) * 64;  // rt
    s_idx[2][u] = (iyb * 128 + ixl) * 64;  // lb
    s_idx[3][u] = (iyb * 128 + ixr) * 64;  // rb
    s_wt[0][u] = xr - x;   // xr_x
    s_wt[1][u] = x - xl;   // xl_x
    s_wt[2][u] = yy - yt;  // yt_y
    s_wt[3][u] = yb - yy;  // yb_y
  }
  __syncthreads();
  // No further barriers: everything below is wave/lane-local.

  const int px15 = lane & 15;
  const int cgrp = lane >> 4;  // 0..3

  float bias4[4];
  #pragma unroll
  for (int j = 0; j < 4; ++j) bias4[j] = biasg[j * 16 + px15];

  f32x4 acc[2][4];
  #pragma unroll
  for (int p = 0; p < 2; ++p)
    #pragma unroll
    for (int j = 0; j < 4; ++j)
      acc[p][j] = (f32x4){bias4[j], bias4[j], bias4[j], bias4[j]};

  for (int di = 0; di < 3; ++di) {
    // B fragments for this di (L2-resident, 24KB total)
    bf16x8 Bf[8];
    #pragma unroll
    for (int jk = 0; jk < 8; ++jk)
      Bf[jk] = __builtin_bit_cast(bf16x8, wsBq[(di * 8 + jk) * 64 + lane]);

    #pragma unroll
    for (int p = 0; p < 2; ++p) {
      const int up = (wave * 2 + p) * 16 + px15;   // this lane's pixel
      const int u  = di * 128 + up;
      // broadcast LDS reads (all 4 lane-groups share the same 16 px)
      const int i0 = s_idx[0][u], i1 = s_idx[1][u];
      const int i2 = s_idx[2][u], i3 = s_idx[3][u];
      const float xr_x = s_wt[0][u], xl_x = s_wt[1][u];
      const float yt_y = s_wt[2][u], yb_y = s_wt[3][u];
      const bool need = ((xr_x != 0.f) || (xl_x != 0.f)) &&
                        ((yb_y != 0.f) || (yt_y != 0.f));

      #pragma unroll
      for (int kstep = 0; kstep < 2; ++kstep) {
        uint4 aq = make_uint4(0u, 0u, 0u, 0u);
        if (need) {
          const int c0 = 4 * cgrp + 32 * kstep;
          // h=0: channels c0..c0+3 ; h=1: channels c0+16..c0+19
          float4 lt0 = *reinterpret_cast<const float4*>(fmapb + i0 + c0);
          float4 rt0 = *reinterpret_cast<const float4*>(fmapb + i1 + c0);
          float4 lb0 = *reinterpret_cast<const float4*>(fmapb + i2 + c0);
          float4 rb0 = *reinterpret_cast<const float4*>(fmapb + i3 + c0);
          float4 lt1 = *reinterpret_cast<const float4*>(fmapb + i0 + c0 + 16);
          float4 rt1 = *reinterpret_cast<const float4*>(fmapb + i1 + c0 + 16);
          float4 lb1 = *reinterpret_cast<const float4*>(fmapb + i2 + c0 + 16);
          float4 rb1 = *reinterpret_cast<const float4*>(fmapb + i3 + c0 + 16);
          float v0 = (xr_x * lt0.x + xl_x * lb0.x) * yb_y + (xr_x * rt0.x + xl_x * rb0.x) * yt_y;
          float v1 = (xr_x * lt0.y + xl_x * lb0.y) * yb_y + (xr_x * rt0.y + xl_x * rb0.y) * yt_y;
          float v2 = (xr_x * lt0.z + xl_x * lb0.z) * yb_y + (xr_x * rt0.z + xl_x * rb0.z) * yt_y;
          float v3 = (xr_x * lt0.w + xl_x * lb0.w) * yb_y + (xr_x * rt0.w + xl_x * rb0.w) * yt_y;
          float v4 = (xr_x * lt1.x + xl_x * lb1.x) * yb_y + (xr_x * rt1.x + xl_x * rb1.x) * yt_y;
          float v5 = (xr_x * lt1.y + xl_x * lb1.y) * yb_y + (xr_x * rt1.y + xl_x * rb1.y) * yt_y;
          float v6 = (xr_x * lt1.z + xl_x * lb1.z) * yb_y + (xr_x * rt1.z + xl_x * rb1.z) * yt_y;
          float v7 = (xr_x * lt1.w + xl_x * lb1.w) * yb_y + (xr_x * rt1.w + xl_x * rb1.w) * yt_y;
          aq.x = (unsigned)f2bf(v0) | ((unsigned)f2bf(v1) << 16);
          aq.y = (unsigned)f2bf(v2) | ((unsigned)f2bf(v3) << 16);
          aq.z = (unsigned)f2bf(v4) | ((unsigned)f2bf(v5) << 16);
          aq.w = (unsigned)f2bf(v6) | ((unsigned)f2bf(v7) << 16);
        }
        bf16x8 a = __builtin_bit_cast(bf16x8, aq);
        #pragma unroll
        for (int j = 0; j < 4; ++j)
          acc[p][j] = __builtin_amdgcn_mfma_f32_16x16x32_bf16(a, Bf[j * 2 + kstep],
                                                              acc[p][j], 0, 0, 0);
      }
    }
  }

  // ---- Epilogue: ReLU (bias pre-folded); C/D: col=lane&15, row=(lane>>4)*4+reg ----
  float* outb = out + ((size_t)(b * 128 + oi) * 128) * 64;
  #pragma unroll
  for (int p = 0; p < 2; ++p) {
    int pxB = (wave * 2 + p) * 16 + (lane >> 4) * 4;
    #pragma unroll
    for (int j = 0; j < 4; ++j) {
      int fch = j * 16 + px15;
      #pragma unroll
      for (int reg = 0; reg < 4; ++reg) {
        outb[(size_t)(pxB + reg) * 64 + fch] = fmaxf(acc[p][j][reg], 0.f);
      }
    }
  }
}

extern "C" void kernel_launch(void* const* d_in, const int* in_sizes, int n_in,
                              void* d_out, int out_size, void* d_ws, size_t ws_size,
                              hipStream_t stream) {
  const float* fmap   = (const float*)d_in[0];
  const float* y2     = (const float*)d_in[1];
  const float* conv_w = (const float*)d_in[2];
  const float* gamma  = (const float*)d_in[3];
  const float* beta   = (const float*)d_in[4];
  const float* mean   = (const float*)d_in[5];
  const float* var    = (const float*)d_in[6];
  float* outp = (float*)d_out;

  unsigned short* wsB = (unsigned short*)d_ws;
  float* bias = (float*)((char*)d_ws + 24576);

  prep_kernel<<<48, 256, 0, stream>>>(conv_w, gamma, beta, mean, var, wsB, bias);
  main_kernel<<<1024, 256, 0, stream>>>(fmap, y2, (const uint4*)d_ws, bias, outp);
}

// Round 5
// 32.214 us; speedup vs baseline: 1.5141x; 1.5141x over previous
//
#include <hip/hip_runtime.h>

typedef __bf16 bf16x8 __attribute__((ext_vector_type(8)));
typedef float f32x4 __attribute__((ext_vector_type(4)));

__device__ __forceinline__ unsigned short f2bf(float f) {
  __bf16 h = (__bf16)f;
  return __builtin_bit_cast(unsigned short, h);
}

// d_ws layout: [0, 24576) bytes: wsB bf16 fragment-ordered (12288 shorts)
//              [24576, 24832): bias (64 floats)
// wsB flat idx = (((di*4 + jblk)*2 + kstep)*64 + lane)*8 + i
//   c   = kstep*32 + 4*(lane>>4) + (i&3) + 16*(i>>2)
//   fch = jblk*16 + (lane&15)
__global__ __launch_bounds__(256) void prep_kernel(
    const float* __restrict__ conv_w, const float* __restrict__ gamma,
    const float* __restrict__ beta, const float* __restrict__ mean,
    const float* __restrict__ var, unsigned short* __restrict__ wsB,
    float* __restrict__ bias) {
  int idx = blockIdx.x * 256 + threadIdx.x;
  if (idx >= 12288) return;
  int di    = idx >> 12;
  int r     = idx & 4095;
  int jblk  = r >> 10;
  int r2    = r & 1023;
  int kstep = r2 >> 9;
  int r3    = r2 & 511;
  int lane  = r3 >> 3;
  int i     = r3 & 7;
  int c   = kstep * 32 + 4 * (lane >> 4) + (i & 3) + 16 * (i >> 2);
  int fch = jblk * 16 + (lane & 15);
  float s = gamma[fch] * rsqrtf(var[fch] + 1e-3f);
  float v = conv_w[((di * 3 + 0) * 64 + c) * 64 + fch]
          + conv_w[((di * 3 + 1) * 64 + c) * 64 + fch]
          + conv_w[((di * 3 + 2) * 64 + c) * 64 + fch];
  wsB[idx] = f2bf(v * s);
  if (idx < 64) bias[idx] = beta[idx] - mean[idx] * (gamma[idx] * rsqrtf(var[idx] + 1e-3f));
}

// Fully wave-autonomous: no __syncthreads anywhere. Each wave owns 32 pixels
// (pxblks 2w,2w+1): computes their coords, samples into a private LDS slab,
// and runs its own MFMAs. Within-wave LDS producer->consumer is ordered by
// the in-order DS pipe + compiler lgkmcnt; wave_barrier pins code motion.
__global__ __launch_bounds__(256, 4) void main_kernel(
    const float* __restrict__ fmap, const float* __restrict__ y2,
    const uint4* __restrict__ wsBq, const float* __restrict__ biasg,
    float* __restrict__ out) {
  __shared__ int   s_idx[4][384];
  __shared__ float s_wt[4][384];
  __shared__ uint2 fsA[4][4][64][2];  // [wave][pl*2+kstep][lane''][h], 16KB

  const int t    = threadIdx.x;
  const int lane = t & 63;
  const int wave = t >> 6;
  // XCD swizzle: pin one batch (4.2MB fmap ~ one XCD L2) per XCD
  const int b  = blockIdx.x & 7;
  const int oi = blockIdx.x >> 3;
  const float* fmapb = fmap + (size_t)b * (128 * 128 * 64);

  // ---- Phase 0 (wave-local): coords/weights for this wave's 32 px x 3 di ----
  #pragma unroll
  for (int it = 0; it < 2; ++it) {
    int e = lane + 64 * it;
    if (e < 96) {
      int di  = e >> 5;
      int upl = e & 31;
      int up  = wave * 32 + upl;
      int u   = di * 128 + up;
      int j   = u / 3;
      int a   = u - j * 3;
      const float4* yp = reinterpret_cast<const float4*>(
          y2 + ((size_t)(b * 128 + oi) * 128 + j) * 8);
      float4 xv = yp[0];
      float4 yv = yp[1];

      float hi01 = fmaxf(xv.x, xv.y), lo01 = fminf(xv.x, xv.y);
      float hi23 = fmaxf(xv.z, xv.w), lo23 = fminf(xv.z, xv.w);
      float top1 = fmaxf(hi01, hi23);
      float top2 = fmaxf(fminf(hi01, hi23), (hi01 >= hi23) ? lo01 : lo23);
      float w = fminf(fmaxf(top1, 1.f), 127.f) + fminf(fmaxf(top2, 1.f), 127.f);

      hi01 = fmaxf(yv.x, yv.y); lo01 = fminf(yv.x, yv.y);
      hi23 = fmaxf(yv.z, yv.w); lo23 = fminf(yv.z, yv.w);
      top1 = fmaxf(hi01, hi23);
      top2 = fmaxf(fminf(hi01, hi23), (hi01 >= hi23) ? lo01 : lo23);
      float h = fminf(fmaxf(top1, 1.f), 127.f) + fminf(fmaxf(top2, 1.f), 127.f);

      float x, yy;
      if (a == 0)      { x = ((float)j - 1.0f) - w / 3.0f;  yy = ((float)oi - 1.0f) - h / 3.0f; }
      else if (a == 1) { x = (float)j + w * 1e-10f;         yy = (float)oi + h * 1e-10f; }
      else             { x = ((float)j + 1.0f) + w / 3.0f;  yy = ((float)oi + 1.0f) + h / 3.0f; }

      float xl = fminf(fmaxf(floorf(x), 0.f), 127.f);
      float xr = fminf(fmaxf(ceilf(x),  0.f), 127.f);
      float yt = fminf(fmaxf(floorf(yy), 0.f), 127.f);
      float yb = fminf(fmaxf(ceilf(yy),  0.f), 127.f);
      int ixl = (int)xl, ixr = (int)xr, iyt = (int)yt, iyb = (int)yb;
      s_idx[0][u] = (iyt * 128 + ixl) * 64;  // lt
      s_idx[1][u] = (iyt * 128 + ixr) * 64;  // rt
      s_idx[2][u] = (iyb * 128 + ixl) * 64;  // lb
      s_idx[3][u] = (iyb * 128 + ixr) * 64;  // rb
      s_wt[0][u] = xr - x;   // xr_x
      s_wt[1][u] = x - xl;   // xl_x
      s_wt[2][u] = yy - yt;  // yt_y
      s_wt[3][u] = yb - yy;  // yb_y
    }
  }
  __builtin_amdgcn_wave_barrier();

  const int px15 = lane & 15;
  float bias4[4];
  #pragma unroll
  for (int j = 0; j < 4; ++j) bias4[j] = biasg[j * 16 + px15];

  f32x4 acc[2][4];
  #pragma unroll
  for (int p = 0; p < 2; ++p)
    #pragma unroll
    for (int j = 0; j < 4; ++j)
      acc[p][j] = (f32x4){bias4[j], bias4[j], bias4[j], bias4[j]};

  const int cg    = lane & 15;          // channel quad for sampling
  const int g     = cg & 3;
  const int hh    = (cg >> 2) & 1;
  const int kstepS= cg >> 3;
  const int upg   = lane >> 4;          // pixel-subindex within iteration
  const int lsr   = lane ^ (2 * (lane >> 4));  // read-side swizzle

  for (int di = 0; di < 3; ++di) {
    // B fragments for this di (L2-resident, 24KB total)
    bf16x8 Bf[8];
    #pragma unroll
    for (int jk = 0; jk < 8; ++jk)
      Bf[jk] = __builtin_bit_cast(bf16x8, wsBq[(di * 8 + jk) * 64 + lane]);

    // ---- Sampling: 32 px x 16 channel-quads, 16 lanes share a pixel ----
    #pragma unroll 4
    for (int r = 0; r < 8; ++r) {
      int upl = r * 4 + upg;            // 0..31
      int up  = wave * 32 + upl;
      int u   = di * 128 + up;
      // broadcast LDS reads (16 lanes share the same u)
      float xr_x = s_wt[0][u], xl_x = s_wt[1][u];
      float yt_y = s_wt[2][u], yb_y = s_wt[3][u];
      bool need = ((xr_x != 0.f) || (xl_x != 0.f)) &&
                  ((yb_y != 0.f) || (yt_y != 0.f));
      uint2 q = make_uint2(0u, 0u);
      if (need) {
        int c0 = cg * 4;
        int i0 = s_idx[0][u], i1 = s_idx[1][u];
        int i2 = s_idx[2][u], i3 = s_idx[3][u];
        float4 lt = *reinterpret_cast<const float4*>(fmapb + i0 + c0);
        float4 rt = *reinterpret_cast<const float4*>(fmapb + i1 + c0);
        float4 lb = *reinterpret_cast<const float4*>(fmapb + i2 + c0);
        float4 rb = *reinterpret_cast<const float4*>(fmapb + i3 + c0);
        float v0 = (xr_x * lt.x + xl_x * lb.x) * yb_y + (xr_x * rt.x + xl_x * rb.x) * yt_y;
        float v1 = (xr_x * lt.y + xl_x * lb.y) * yb_y + (xr_x * rt.y + xl_x * rb.y) * yt_y;
        float v2 = (xr_x * lt.z + xl_x * lb.z) * yb_y + (xr_x * rt.z + xl_x * rb.z) * yt_y;
        float v3 = (xr_x * lt.w + xl_x * lb.w) * yb_y + (xr_x * rt.w + xl_x * rb.w) * yt_y;
        q.x = (unsigned)f2bf(v0) | ((unsigned)f2bf(v1) << 16);
        q.y = (unsigned)f2bf(v2) | ((unsigned)f2bf(v3) << 16);
      }
      int lpp = ((upl & 15) | (g << 4)) ^ (g << 1);  // bank swizzle
      fsA[wave][(upl >> 4) * 2 + kstepS][lpp][hh] = q;
    }
    __builtin_amdgcn_wave_barrier();

    // ---- MFMA: wave reads its own slab; pxblks {2w, 2w+1} x 4 fch blocks ----
    #pragma unroll
    for (int kstep = 0; kstep < 2; ++kstep) {
      #pragma unroll
      for (int p = 0; p < 2; ++p) {
        bf16x8 a = __builtin_bit_cast(bf16x8,
            *reinterpret_cast<const uint4*>(&fsA[wave][p * 2 + kstep][lsr][0]));
        #pragma unroll
        for (int j = 0; j < 4; ++j)
          acc[p][j] = __builtin_amdgcn_mfma_f32_16x16x32_bf16(a, Bf[j * 2 + kstep],
                                                              acc[p][j], 0, 0, 0);
      }
    }
    __builtin_amdgcn_wave_barrier();
  }

  // ---- Epilogue: ReLU (bias pre-folded); C/D: col=lane&15, row=(lane>>4)*4+reg ----
  float* outb = out + ((size_t)(b * 128 + oi) * 128) * 64;
  #pragma unroll
  for (int p = 0; p < 2; ++p) {
    int pxB = (wave * 2 + p) * 16 + (lane >> 4) * 4;
    #pragma unroll
    for (int j = 0; j < 4; ++j) {
      int fch = j * 16 + px15;
      #pragma unroll
      for (int reg = 0; reg < 4; ++reg) {
        outb[(size_t)(pxB + reg) * 64 + fch] = fmaxf(acc[p][j][reg], 0.f);
      }
    }
  }
}

extern "C" void kernel_launch(void* const* d_in, const int* in_sizes, int n_in,
                              void* d_out, int out_size, void* d_ws, size_t ws_size,
                              hipStream_t stream) {
  const float* fmap   = (const float*)d_in[0];
  const float* y2     = (const float*)d_in[1];
  const float* conv_w = (const float*)d_in[2];
  const float* gamma  = (const float*)d_in[3];
  const float* beta   = (const float*)d_in[4];
  const float* mean   = (const float*)d_in[5];
  const float* var    = (const float*)d_in[6];
  float* outp = (float*)d_out;

  unsigned short* wsB = (unsigned short*)d_ws;
  float* bias = (float*)((char*)d_ws + 24576);

  prep_kernel<<<48, 256, 0, stream>>>(conv_w, gamma, beta, mean, var, wsB, bias);
  main_kernel<<<1024, 256, 0, stream>>>(fmap, y2, (const uint4*)d_ws, bias, outp);
}